// Round 3
// baseline (82.546 us; speedup 1.0000x reference)
//
#include <hip/hip_runtime.h>
#include <math.h>

#define DIM 64
#define BATCH 4096

// clang-native vector type (true vector-of-scalars; NT builtin needs it)
typedef float vf4 __attribute__((ext_vector_type(4)));

// FOUR waves per batch element (R3; was 2). Closed-form amplitudes of
// psi = D(alpha) S(r) |0>:
//   psi_{n+1} = (alpha*(1+tanh r)*psi_n - tanh r*sqrt(n)*psi_{n-1}) / sqrt(n+1)
// All 64 lanes run the 63-step recurrence redundantly (wave-uniform VALU,
// ~0.3us, no shuffles in the chain); lane n latches psi_n. Butterfly-
// normalize, then each wave writes a QUARTER of rho[b] = psi psi^T.
//
// R2 established (kernel absent from top-5; fill = 46us):
//   dur_us ~= 46 (harness poison fill) + gap + kernel(~30us).
//   Output is complex64 interleaved (134 MB): interleaved writes passed
//   correctness and didn't fault -> that IS the live path. Kernel at
//   ~4.5 TB/s vs fill's 5.8 TB/s on the same path.
// R3 changes: 4-wave split (8KB per wave, grid 4096 = 16 blocks/CU ->
// staggered block starts smooth the store pipe) + NT stores restored at
// full occupancy (R1 had NT only at 16 waves/CU).
__global__ __launch_bounds__(256) void qencoder_kernel(const float* __restrict__ x,
                                                       float* __restrict__ out,
                                                       int interleaved) {
    const int lane = threadIdx.x & 63;
    const int gw = blockIdx.x * (blockDim.x >> 6) + (threadIdx.x >> 6);  // global wave
    const int b = gw >> 2;        // batch element
    const int quarter = gw & 3;   // which 16-row quarter this wave stores

    const float TANH_R = 0.46211715726f;   // tanh(0.5)
    const float alpha = 0.5f * x[b];
    const float c1 = alpha * (1.0f + TANH_R);   // alpha * e^r / cosh r

    // 63-step recurrence, fully unrolled (sqrt(n), rsqrt(n+1) fold to literals)
    float pm1 = 1.0f;           // psi_{n-1} -> starts as psi_0
    float p   = c1;             // psi_1 = c1 * psi_0
    float v = (lane == 0) ? 1.0f : 0.0f;
    if (lane == 1) v = p;
    #pragma unroll
    for (int n = 1; n < DIM - 1; ++n) {
        float pn = (c1 * p - TANH_R * sqrtf((float)n) * pm1) * rsqrtf((float)(n + 1));
        pm1 = p;
        p = pn;
        if (lane == n + 1) v = pn;
    }

    // normalize (truncated-64 norm, matches reference semantics)
    float n2 = v * v;
    #pragma unroll
    for (int off = 32; off; off >>= 1) n2 += __shfl_xor(n2, off, 64);
    v *= rsqrtf(n2);

    if (interleaved) {
        // complex64: (re, im) pairs, im = 0. vf4 = 2 complex elements.
        // Wave instruction = 1KB contiguous (2 rows x 512B). This is the
        // live path (R2-proven).
        const int cp = lane & 31;
        const int rs = lane >> 5;
        float pc0 = __shfl(v, 2 * cp, 64);
        float pc1 = __shfl(v, 2 * cp + 1, 64);
        vf4* o4 = (vf4*)out + (size_t)b * (DIM * DIM / 2);
        #pragma unroll
        for (int i = 0; i < DIM / 8; ++i) {          // 8 x 1KB per wave
            int ii = quarter * (DIM / 8) + i;        // this wave's row-pairs
            int row = 2 * ii + rs;
            float vr = __shfl(v, row, 64);
            vf4 val = {vr * pc0, 0.f, vr * pc1, 0.f};
            __builtin_nontemporal_store(val, &o4[row * (DIM / 2) + cp]);
        }
    } else {
        // defensive real-only path (not live per R2 evidence)
        const int c  = lane & 15;
        const int rq = lane >> 4;
        float pc0 = __shfl(v, 4 * c + 0, 64);
        float pc1 = __shfl(v, 4 * c + 1, 64);
        float pc2 = __shfl(v, 4 * c + 2, 64);
        float pc3 = __shfl(v, 4 * c + 3, 64);
        vf4* o4 = (vf4*)out + (size_t)b * (DIM * DIM / 4);
        #pragma unroll
        for (int i = 0; i < DIM / 16; ++i) {         // 4 x 1KB per wave
            int ii = quarter * (DIM / 16) + i;
            int row = 4 * ii + rq;
            float vr = __shfl(v, row, 64);
            vf4 val = {vr * pc0, vr * pc1, vr * pc2, vr * pc3};
            __builtin_nontemporal_store(val, &o4[row * (DIM / 4) + c]);
        }
    }
}

extern "C" void kernel_launch(void* const* d_in, const int* in_sizes, int n_in,
                              void* d_out, int out_size, void* d_ws, size_t ws_size,
                              hipStream_t stream) {
    const float* x = (const float*)d_in[0];   // (4096,) float32
    float* out = (float*)d_out;

    const int N = BATCH * DIM * DIM;
    const int interleaved = (out_size >= 2 * N) ? 1 : 0;

    // 4 waves per batch element -> 16384 waves -> 4096 blocks of 4 waves
    qencoder_kernel<<<BATCH * 4 / 4, 256, 0, stream>>>(x, out, interleaved);
}

// Round 4
// 79.302 us; speedup vs baseline: 1.0409x; 1.0409x over previous
//
#include <hip/hip_runtime.h>
#include <math.h>

#define DIM 64
#define BATCH 4096

// clang-native vector type (true vector-of-scalars, 16 B stores)
typedef float vf4 __attribute__((ext_vector_type(4)));

// TWO waves per batch element. Closed-form amplitudes of psi = D(alpha) S(r)|0>:
//   psi_{n+1} = (alpha*(1+tanh r)*psi_n - tanh r*sqrt(n)*psi_{n-1}) / sqrt(n+1)
// All 64 lanes run the 63-step recurrence redundantly; lane n latches psi_n.
// Butterfly-normalize, then each wave writes HALF the rows of
// rho[b] = psi psi^T (complex64 interleaved, imag = 0 — live path per R2).
//
// R4 change (theory: store-issue dilution): R1-R3 had a __shfl (ds_bpermute +
// lgkmcnt(0) wait + 2 VALU) dependency chain in front of EVERY 1KB store ->
// per-wave store duty cycle ~15%. The 6.0 TB/s harness fill does back-to-back
// stores at 8% occupancy — proving issue density, not occupancy, is what
// matters. So: hoist ALL shuffles/multiplies into a pre-pass filling
// vals[16] in registers, leaving a pure 16x back-to-back store loop
// structurally identical to the fill. Plain (non-NT) stores = the proven
// 6 TB/s path. Occupancy/NT macro-levers measured null (R2/R3).
__global__ __launch_bounds__(256) void qencoder_kernel(const float* __restrict__ x,
                                                       float* __restrict__ out,
                                                       int interleaved) {
    const int lane = threadIdx.x & 63;
    const int gw = blockIdx.x * (blockDim.x >> 6) + (threadIdx.x >> 6);  // global wave
    const int b = gw >> 1;        // batch element
    const int half = gw & 1;      // which 32-row half this wave stores

    const float TANH_R = 0.46211715726f;   // tanh(0.5)
    const float alpha = 0.5f * x[b];
    const float c1 = alpha * (1.0f + TANH_R);   // alpha * e^r / cosh r

    // 63-step recurrence, fully unrolled (sqrt(n), rsqrt(n+1) fold to literals)
    float pm1 = 1.0f;           // psi_{n-1} -> starts as psi_0
    float p   = c1;             // psi_1 = c1 * psi_0
    float v = (lane == 0) ? 1.0f : 0.0f;
    if (lane == 1) v = p;
    #pragma unroll
    for (int n = 1; n < DIM - 1; ++n) {
        float pn = (c1 * p - TANH_R * sqrtf((float)n) * pm1) * rsqrtf((float)(n + 1));
        pm1 = p;
        p = pn;
        if (lane == n + 1) v = pn;
    }

    // normalize
    float n2 = v * v;
    #pragma unroll
    for (int off = 32; off; off >>= 1) n2 += __shfl_xor(n2, off, 64);
    v *= rsqrtf(n2);

    if (interleaved) {
        // complex64: (re, im) pairs, im = 0. vf4 = 2 complex elements.
        // Wave store = 1KB contiguous (2 rows x 512B).
        const int cp = lane & 31;
        const int rs = lane >> 5;
        const float pc0 = __shfl(v, 2 * cp, 64);
        const float pc1 = __shfl(v, 2 * cp + 1, 64);

        // ---- phase 2: ALL shuffles + multiplies, no stores ----
        vf4 vals[16];
        #pragma unroll
        for (int i = 0; i < 16; ++i) {
            int row = 2 * (half * 16 + i) + rs;
            float vr = __shfl(v, row, 64);
            vals[i].x = vr * pc0;
            vals[i].y = 0.f;
            vals[i].z = vr * pc1;
            vals[i].w = 0.f;
        }

        // ---- phase 3: pure back-to-back stores (fill-shaped stream) ----
        vf4* o4 = (vf4*)out + (size_t)b * (DIM * DIM / 2);
        #pragma unroll
        for (int i = 0; i < 16; ++i) {
            int row = 2 * (half * 16 + i) + rs;
            o4[row * (DIM / 2) + cp] = vals[i];
        }
    } else {
        // defensive real-only path (not live per R2 evidence), same structure
        const int c  = lane & 15;
        const int rq = lane >> 4;
        const float pc0 = __shfl(v, 4 * c + 0, 64);
        const float pc1 = __shfl(v, 4 * c + 1, 64);
        const float pc2 = __shfl(v, 4 * c + 2, 64);
        const float pc3 = __shfl(v, 4 * c + 3, 64);

        vf4 vals[8];
        #pragma unroll
        for (int i = 0; i < 8; ++i) {
            int row = 4 * (half * 8 + i) + rq;
            float vr = __shfl(v, row, 64);
            vals[i].x = vr * pc0;
            vals[i].y = vr * pc1;
            vals[i].z = vr * pc2;
            vals[i].w = vr * pc3;
        }

        vf4* o4 = (vf4*)out + (size_t)b * (DIM * DIM / 4);
        #pragma unroll
        for (int i = 0; i < 8; ++i) {
            int row = 4 * (half * 8 + i) + rq;
            o4[row * (DIM / 4) + c] = vals[i];
        }
    }
}

extern "C" void kernel_launch(void* const* d_in, const int* in_sizes, int n_in,
                              void* d_out, int out_size, void* d_ws, size_t ws_size,
                              hipStream_t stream) {
    const float* x = (const float*)d_in[0];   // (4096,) float32
    float* out = (float*)d_out;

    const int N = BATCH * DIM * DIM;
    const int interleaved = (out_size >= 2 * N) ? 1 : 0;

    // 2 waves per batch element -> 8192 waves -> 2048 blocks of 4 waves
    qencoder_kernel<<<BATCH * 2 / 4, 256, 0, stream>>>(x, out, interleaved);
}